// Round 8
// baseline (4796.328 us; speedup 1.0000x reference)
//
#include <hip/hip_runtime.h>
#include <cstdint>
#include <cmath>

#define NN 8192
#define DD 512
#define KP1 31                      // k+1 with k=30
#define HALF_EDGES (NN * KP1)       // 253952
#define TM 16
#define TN 64
#define KC 64

// ---------------- Threefry-2x32-20, key = (0, 42)  (jax.random.key(42)) ----
__device__ __forceinline__ uint32_t rotl32(uint32_t v, int s) {
  return (v << s) | (v >> (32 - s));
}

__device__ __forceinline__ void threefry2x32_42(uint32_t x0, uint32_t x1,
                                                uint32_t& o0, uint32_t& o1) {
  const uint32_t ks0 = 0u, ks1 = 42u;
  const uint32_t ks2 = 0x1BD11BDAu ^ ks0 ^ ks1;
  x0 += ks0; x1 += ks1;
  x0 += x1; x1 = rotl32(x1, 13); x1 ^= x0;
  x0 += x1; x1 = rotl32(x1, 15); x1 ^= x0;
  x0 += x1; x1 = rotl32(x1, 26); x1 ^= x0;
  x0 += x1; x1 = rotl32(x1, 6);  x1 ^= x0;
  x0 += ks1; x1 += ks2 + 1u;
  x0 += x1; x1 = rotl32(x1, 17); x1 ^= x0;
  x0 += x1; x1 = rotl32(x1, 29); x1 ^= x0;
  x0 += x1; x1 = rotl32(x1, 16); x1 ^= x0;
  x0 += x1; x1 = rotl32(x1, 24); x1 ^= x0;
  x0 += ks2; x1 += ks0 + 2u;
  x0 += x1; x1 = rotl32(x1, 13); x1 ^= x0;
  x0 += x1; x1 = rotl32(x1, 15); x1 ^= x0;
  x0 += x1; x1 = rotl32(x1, 26); x1 ^= x0;
  x0 += x1; x1 = rotl32(x1, 6);  x1 ^= x0;
  x0 += ks0; x1 += ks1 + 3u;
  x0 += x1; x1 = rotl32(x1, 17); x1 ^= x0;
  x0 += x1; x1 = rotl32(x1, 29); x1 ^= x0;
  x0 += x1; x1 = rotl32(x1, 16); x1 ^= x0;
  x0 += x1; x1 = rotl32(x1, 24); x1 ^= x0;
  x0 += ks1; x1 += ks2 + 4u;
  x0 += x1; x1 = rotl32(x1, 13); x1 ^= x0;
  x0 += x1; x1 = rotl32(x1, 15); x1 ^= x0;
  x0 += x1; x1 = rotl32(x1, 26); x1 ^= x0;
  x0 += x1; x1 = rotl32(x1, 6);  x1 ^= x0;
  x0 += ks2; x1 += ks0 + 5u;
  o0 = x0; o1 = x1;
}

// JAX partitionable-threefry keep decision for flat element index e.
__device__ __forceinline__ bool keep_edge(uint32_t e) {
  uint32_t y0, y1;
  threefry2x32_42(0u, e, y0, y1);
  uint32_t bits = y0 ^ y1;
  float u = __uint_as_float((bits >> 9) | 0x3f800000u) - 1.0f;
  return u < 0.9f;
}

// ---------------- K1: fp32 row norm (numpy pairwise tree) + xn = x/norm ----
// Bit-matches np.linalg.norm(x, axis=1) for contiguous n=512 f32.
__global__ __launch_bounds__(256) void normxn_kernel(const float* __restrict__ x,
                                                     float* __restrict__ xn) {
#pragma clang fp contract(off)
  __shared__ float rowbuf[TM][DD];       // 32 KB
  __shared__ float partial[TM][4];
  __shared__ float nrm[TM];
  int tid = threadIdx.x;
  int rowbase = blockIdx.x * TM;

  for (int p = 0; p < 8; ++p) {
    int f = tid + p * 256;
    int r = f >> 7, k4 = f & 127;
    *(float4*)(&rowbuf[r][k4 << 2]) =
        *(const float4*)(x + (size_t)(rowbase + r) * DD + (k4 << 2));
  }
  __syncthreads();
  if (tid < 64) {
    int r = tid >> 2, q = tid & 3;
    const float* s = &rowbuf[r][q * 128];
    float acc0 = s[0] * s[0], acc1 = s[1] * s[1], acc2 = s[2] * s[2], acc3 = s[3] * s[3];
    float acc4 = s[4] * s[4], acc5 = s[5] * s[5], acc6 = s[6] * s[6], acc7 = s[7] * s[7];
    for (int i = 8; i < 128; i += 8) {
      acc0 += s[i + 0] * s[i + 0];
      acc1 += s[i + 1] * s[i + 1];
      acc2 += s[i + 2] * s[i + 2];
      acc3 += s[i + 3] * s[i + 3];
      acc4 += s[i + 4] * s[i + 4];
      acc5 += s[i + 5] * s[i + 5];
      acc6 += s[i + 6] * s[i + 6];
      acc7 += s[i + 7] * s[i + 7];
    }
    partial[r][q] = ((acc0 + acc1) + (acc2 + acc3)) + ((acc4 + acc5) + (acc6 + acc7));
  }
  __syncthreads();
  if (tid < TM) {
    float S = (partial[tid][0] + partial[tid][1]) + (partial[tid][2] + partial[tid][3]);
    nrm[tid] = sqrtf(S);
  }
  __syncthreads();
  for (int p = 0; p < 8; ++p) {
    int f = tid + p * 256;
    int r = f >> 7, k4 = f & 127;
    float nv = nrm[r];
    float4 v = *(const float4*)(&rowbuf[r][k4 << 2]);
    float4 o;
    o.x = v.x / nv; o.y = v.y / nv; o.z = v.z / nv; o.w = v.w / nv;
    *(float4*)(xn + (size_t)(rowbase + r) * DD + (k4 << 2)) = o;
  }
}

// ---------------- K2: fp32 sim = ONE sequential MUL+ADD chain (no FMA) -----
// Candidate ref rounding: Eigen SSE/no-FMA gebp (jaxlib/TF CPU wheels are
// built without -mfma), numpy no-BLAS fallback dot, or any -O2-compiled naive
// loop: c = round(c + round(a*b)), k ascending 0..511, single accumulator.
__global__ __launch_bounds__(256) void topk_kernel(const float* __restrict__ xn,
                                                   float* __restrict__ vals,
                                                   int* __restrict__ inds) {
#pragma clang fp contract(off)
  __shared__ float As[TM][DD];           // 32 KB
  __shared__ float Bs[KC][TN + 1];       // 16.25 KB
  __shared__ float Cs[TM][TN + 1];       // 4.06 KB
  __shared__ float kval[TM][KP1 + 1];    // 2 KB
  __shared__ int   kidx[TM][KP1 + 1];    // 2 KB

  int tid = threadIdx.x;
  int rowbase = blockIdx.x * TM;

  for (int p = 0; p < 8; ++p) {
    int f = tid + p * 256;
    int r = f >> 7, k4 = f & 127;
    *(float4*)(&As[r][k4 << 2]) =
        *(const float4*)(xn + (size_t)(rowbase + r) * DD + (k4 << 2));
  }
  for (int f = tid; f < TM * KP1; f += 256) {
    int r = f / KP1, s = f - r * KP1;
    kval[r][s] = -1e30f;
    kidx[r][s] = 0;
  }

  int col = tid & 63;
  int rg  = tid >> 6;
  __syncthreads();

  for (int tile = 0; tile < NN / TN; ++tile) {
    int colbase = tile * TN;
    float a0c = 0.f, a1c = 0.f, a2c = 0.f, a3c = 0.f;   // one chain per row
    for (int kc = 0; kc < DD / KC; ++kc) {
      __syncthreads();
      for (int p = 0; p < 4; ++p) {
        int f = tid + p * 256;
        int c = f >> 4, k4 = f & 15;
        float4 v = *(const float4*)(xn + (size_t)(colbase + c) * DD + kc * KC + (k4 << 2));
        Bs[(k4 << 2) + 0][c] = v.x;
        Bs[(k4 << 2) + 1][c] = v.y;
        Bs[(k4 << 2) + 2][c] = v.z;
        Bs[(k4 << 2) + 3][c] = v.w;
      }
      __syncthreads();
      const float* a0 = &As[rg * 4 + 0][kc * KC];
      const float* a1 = &As[rg * 4 + 1][kc * KC];
      const float* a2 = &As[rg * 4 + 2][kc * KC];
      const float* a3 = &As[rg * 4 + 3][kc * KC];
      for (int k = 0; k < KC; ++k) {   // c += a*b with SEPARATE mul/add rounding
        float b = Bs[k][col];
        a0c = a0c + a0[k] * b;
        a1c = a1c + a1[k] * b;
        a2c = a2c + a2[k] * b;
        a3c = a3c + a3[k] * b;
      }
    }
    Cs[rg * 4 + 0][col] = a0c;
    Cs[rg * 4 + 1][col] = a1c;
    Cs[rg * 4 + 2][col] = a2c;
    Cs[rg * 4 + 3][col] = a3c;
    __syncthreads();
    // Serial per-row merge; stable (ascending col, strict compares) ->
    // ties keep lower index first (lax.top_k / stable argsort of -sim).
    if (tid < TM) {
      int r = tid;
      float kmin = kval[r][KP1 - 1];
      for (int c = 0; c < TN; ++c) {
        float v = Cs[r][c];
        if (v > kmin) {
          int pos = KP1 - 1;
          while (pos > 0 && kval[r][pos - 1] < v) {
            kval[r][pos] = kval[r][pos - 1];
            kidx[r][pos] = kidx[r][pos - 1];
            --pos;
          }
          kval[r][pos] = v;
          kidx[r][pos] = colbase + c;
          kmin = kval[r][KP1 - 1];
        }
      }
    }
    __syncthreads();
  }

  for (int f = tid; f < TM * KP1; f += 256) {
    int r = f / KP1, s = f - r * KP1;
    vals[(size_t)(rowbase + r) * KP1 + s] = kval[r][s];
    inds[(rowbase + r) * KP1 + s] = kidx[r][s];
  }
}

// ---------------- K3: degree mass (norm_row + norm_col) --------------------
__global__ __launch_bounds__(256) void norm_kernel(const float* __restrict__ vals,
                                                   const int* __restrict__ inds,
                                                   float* __restrict__ norm) {
  int i = blockIdx.x * blockDim.x + threadIdx.x;
  if (i >= NN) return;
  float s = 0.f;
  for (int t = 0; t < KP1; ++t) {
    float v = vals[i * KP1 + t];
    s += v;
    atomicAdd(&norm[inds[i * KP1 + t]], v);
  }
  atomicAdd(&norm[i], s);
}

// ---------------- K4: normalize + relu + threefry dropout + scatter --------
__global__ __launch_bounds__(256) void scatter_kernel(const float* __restrict__ vals,
                                                      const int* __restrict__ inds,
                                                      const float* __restrict__ norm,
                                                      float* __restrict__ out) {
  int e = blockIdx.x * blockDim.x + threadIdx.x;
  if (e >= HALF_EDGES) return;
  int i = e / KP1;
  int c = inds[e];
  float v = vals[e];
  float nv = v * (1.0f / sqrtf(norm[i])) * (1.0f / sqrtf(norm[c]));
  if (isnan(nv)) nv = 0.f;
  nv = fmaxf(nv, 0.f);                       // relu
  float scaled = nv / 0.9f;                  // /(1 - EDGE_DROPOUT)
  if (keep_edge((uint32_t)e))
    atomicAdd(out + (size_t)i * NN + c, scaled);             // edge (i -> c)
  if (keep_edge((uint32_t)(e + HALF_EDGES)))
    atomicAdd(out + (size_t)c * NN + i, scaled);             // edge (c -> i)
}

// ---------------------------------------------------------------------------
extern "C" void kernel_launch(void* const* d_in, const int* in_sizes, int n_in,
                              void* d_out, int out_size, void* d_ws, size_t ws_size,
                              hipStream_t stream) {
  (void)in_sizes; (void)n_in; (void)ws_size;
  const float* x = (const float*)d_in[0];
  float* out = (float*)d_out;

  // ws layout (~2.1 MB)
  float* vals = (float*)d_ws;                  // 253952 floats
  int*   inds = (int*)(vals + HALF_EDGES);     // 253952 ints
  float* norm = (float*)(inds + HALF_EDGES);   // 8192 floats

  // xn (8192x512 fp32 = 16 MB) parked in the tail of d_out; consumed by
  // topk_kernel before the full-out memset below overwrites it.
  float* xn = out + ((size_t)NN * NN - (size_t)NN * DD);

  hipLaunchKernelGGL(normxn_kernel, dim3(NN / TM), dim3(256), 0, stream, x, xn);
  hipLaunchKernelGGL(topk_kernel, dim3(NN / TM), dim3(256), 0, stream, xn, vals, inds);
  hipMemsetAsync(norm, 0, NN * sizeof(float), stream);
  hipLaunchKernelGGL(norm_kernel, dim3((NN + 255) / 256), dim3(256), 0, stream,
                     vals, inds, norm);
  hipMemsetAsync(d_out, 0, (size_t)out_size * sizeof(float), stream);
  hipLaunchKernelGGL(scatter_kernel, dim3((HALF_EDGES + 255) / 256), dim3(256), 0, stream,
                     vals, inds, norm, out);
}

// Round 10
// 2643.770 us; speedup vs baseline: 1.8142x; 1.8142x over previous
//
#include <hip/hip_runtime.h>
#include <cstdint>
#include <cmath>

#define NN 8192
#define DD 512
#define KP1 31                      // k+1 with k=30
#define HALF_EDGES (NN * KP1)       // 253952

// ---------------- Threefry-2x32-20, key = (0, 42) --------------------------
__device__ __forceinline__ uint32_t rotl32(uint32_t v, int s) {
  return (v << s) | (v >> (32 - s));
}

__device__ __forceinline__ void threefry2x32_42(uint32_t x0, uint32_t x1,
                                                uint32_t& o0, uint32_t& o1) {
  const uint32_t ks0 = 0u, ks1 = 42u;
  const uint32_t ks2 = 0x1BD11BDAu ^ ks0 ^ ks1;
  x0 += ks0; x1 += ks1;
  x0 += x1; x1 = rotl32(x1, 13); x1 ^= x0;
  x0 += x1; x1 = rotl32(x1, 15); x1 ^= x0;
  x0 += x1; x1 = rotl32(x1, 26); x1 ^= x0;
  x0 += x1; x1 = rotl32(x1, 6);  x1 ^= x0;
  x0 += ks1; x1 += ks2 + 1u;
  x0 += x1; x1 = rotl32(x1, 17); x1 ^= x0;
  x0 += x1; x1 = rotl32(x1, 29); x1 ^= x0;
  x0 += x1; x1 = rotl32(x1, 16); x1 ^= x0;
  x0 += x1; x1 = rotl32(x1, 24); x1 ^= x0;
  x0 += ks2; x1 += ks0 + 2u;
  x0 += x1; x1 = rotl32(x1, 13); x1 ^= x0;
  x0 += x1; x1 = rotl32(x1, 15); x1 ^= x0;
  x0 += x1; x1 = rotl32(x1, 26); x1 ^= x0;
  x0 += x1; x1 = rotl32(x1, 6);  x1 ^= x0;
  x0 += ks0; x1 += ks1 + 3u;
  x0 += x1; x1 = rotl32(x1, 17); x1 ^= x0;
  x0 += x1; x1 = rotl32(x1, 29); x1 ^= x0;
  x0 += x1; x1 = rotl32(x1, 16); x1 ^= x0;
  x0 += x1; x1 = rotl32(x1, 24); x1 ^= x0;
  x0 += ks1; x1 += ks2 + 4u;
  x0 += x1; x1 = rotl32(x1, 13); x1 ^= x0;
  x0 += x1; x1 = rotl32(x1, 15); x1 ^= x0;
  x0 += x1; x1 = rotl32(x1, 26); x1 ^= x0;
  x0 += x1; x1 = rotl32(x1, 6);  x1 ^= x0;
  x0 += ks2; x1 += ks0 + 5u;
  o0 = x0; o1 = x1;
}

__device__ __forceinline__ bool keep_edge(uint32_t e) {
  uint32_t y0, y1;
  threefry2x32_42(0u, e, y0, y1);
  uint32_t bits = y0 ^ y1;
  float u = __uint_as_float((bits >> 9) | 0x3f800000u) - 1.0f;
  return u < 0.9f;
}

// ---------------- K1: fp32 row norm (numpy pairwise tree) ------------------
// Bit-matches np.linalg.norm(x, axis=1) for contiguous n=512 f32 (verified R8).
__global__ __launch_bounds__(256) void rownorm_kernel(const float* __restrict__ x,
                                                      float* __restrict__ nrm) {
#pragma clang fp contract(off)
  __shared__ float rowbuf[16][DD];
  __shared__ float partial[16][4];
  int tid = threadIdx.x;
  int rowbase = blockIdx.x * 16;

  for (int p = 0; p < 8; ++p) {
    int f = tid + p * 256;
    int r = f >> 7, k4 = f & 127;
    *(float4*)(&rowbuf[r][k4 << 2]) =
        *(const float4*)(x + (size_t)(rowbase + r) * DD + (k4 << 2));
  }
  __syncthreads();
  if (tid < 64) {
    int r = tid >> 2, q = tid & 3;
    const float* s = &rowbuf[r][q * 128];
    float a0 = s[0]*s[0], a1 = s[1]*s[1], a2 = s[2]*s[2], a3 = s[3]*s[3];
    float a4 = s[4]*s[4], a5 = s[5]*s[5], a6 = s[6]*s[6], a7 = s[7]*s[7];
    for (int i = 8; i < 128; i += 8) {
      a0 += s[i+0]*s[i+0]; a1 += s[i+1]*s[i+1];
      a2 += s[i+2]*s[i+2]; a3 += s[i+3]*s[i+3];
      a4 += s[i+4]*s[i+4]; a5 += s[i+5]*s[i+5];
      a6 += s[i+6]*s[i+6]; a7 += s[i+7]*s[i+7];
    }
    partial[r][q] = ((a0 + a1) + (a2 + a3)) + ((a4 + a5) + (a6 + a7));
  }
  __syncthreads();
  if (tid < 16) {
    float S = (partial[tid][0] + partial[tid][1]) + (partial[tid][2] + partial[tid][3]);
    nrm[rowbase + tid] = sqrtf(S);
  }
}

// ---------------- K2: 128x128-tile sim GEMM (no-FMA chains) ----------------
// Each lane: 8 rows (contiguous) x 8 cols (strided 8), single sequential
// mul+add chain per element, k ascending 0..511 (verified rounding class).
// LDS swizzle: A slot = (k4 + (row>>3)) & 15; B slot = (k4 + col) & 15.
__global__ __launch_bounds__(256, 2) void gemm_kernel(const float* __restrict__ x,
                                                      const float* __restrict__ nrm,
                                                      float* __restrict__ out) {
#pragma clang fp contract(off)
  extern __shared__ char smem[];
  float4* AsF4 = (float4*)smem;              // [128 rows][16 slots]  32 KB
  float4* BsF4 = (float4*)(smem + 32768);    // [128 cols][16 slots]  32 KB

  const int tid = threadIdx.x;
  const int rb = blockIdx.y * 128;
  const int cb = blockIdx.x * 128;
  const int m = tid & 15;                    // staging k4
  const int g = tid >> 4;                    // staging row/col base (0..15)

  float nA[8], nB[8];
  #pragma unroll
  for (int p = 0; p < 8; ++p) {
    nA[p] = nrm[rb + g + 16 * p];
    nB[p] = nrm[cb + g + 16 * p];
  }

  const int lane = tid & 63, wave = tid >> 6;
  const int wr = wave >> 1, wc = wave & 1;
  const int lr = lane >> 3, lc = lane & 7;
  const int r0 = wr * 64 + lr * 8;           // 8 contiguous rows r0..r0+7
  const int c0 = wc * 64 + lc;               // cols c0 + 8j, j=0..7
  const int rsw = r0 >> 3;                   // = wr*8 + lr, A-swizzle base

  float acc[8][8];
  #pragma unroll
  for (int i = 0; i < 8; ++i)
    #pragma unroll
    for (int j = 0; j < 8; ++j) acc[i][j] = 0.f;

  const float4* xv = (const float4*)x;

  for (int kc = 0; kc < 8; ++kc) {
    __syncthreads();
    #pragma unroll
    for (int p = 0; p < 8; ++p) {
      int r = g + 16 * p;                    // 0..127
      float4 va = xv[(size_t)(rb + r) * 128 + kc * 16 + m];
      va.x = va.x / nA[p]; va.y = va.y / nA[p];
      va.z = va.z / nA[p]; va.w = va.w / nA[p];
      AsF4[r * 16 + ((m + (r >> 3)) & 15)] = va;
      float4 vb = xv[(size_t)(cb + r) * 128 + kc * 16 + m];
      vb.x = vb.x / nB[p]; vb.y = vb.y / nB[p];
      vb.z = vb.z / nB[p]; vb.w = vb.w / nB[p];
      BsF4[r * 16 + ((m + r) & 15)] = vb;
    }
    __syncthreads();

    #pragma unroll 2
    for (int k4 = 0; k4 < 16; ++k4) {
      float4 av[8], bv[8];
      int tA = (k4 + rsw) & 15;              // FIXED: inverse of store swizzle
      #pragma unroll
      for (int i = 0; i < 8; ++i) av[i] = AsF4[(r0 + i) * 16 + tA];
      #pragma unroll
      for (int j = 0; j < 8; ++j)
        bv[j] = BsF4[(c0 + 8 * j) * 16 + ((k4 + lc + 8 * j) & 15)];
      #pragma unroll
      for (int kk = 0; kk < 4; ++kk) {
        #pragma unroll
        for (int i = 0; i < 8; ++i) {
          float a = ((const float*)&av[i])[kk];
          #pragma unroll
          for (int j = 0; j < 8; ++j) {
            float b = ((const float*)&bv[j])[kk];
            acc[i][j] = acc[i][j] + a * b;   // separate mul+add, k ascending
          }
        }
      }
    }
  }

  // Write-out via LDS re-tile (stride 129 -> bank-balanced scatter).
  float* Cs = (float*)smem;
  float4* outv = (float4*)out;
  for (int half = 0; half < 2; ++half) {
    __syncthreads();
    if (wr == half) {
      #pragma unroll
      for (int i = 0; i < 8; ++i)
        #pragma unroll
        for (int j = 0; j < 8; ++j)
          Cs[(lr * 8 + i) * 129 + wc * 64 + 8 * j + lc] = acc[i][j];
    }
    __syncthreads();
    #pragma unroll
    for (int q = 0; q < 8; ++q) {
      int f2 = tid + q * 256;
      int rl = f2 >> 5, c4 = f2 & 31;
      float4 o;
      o.x = Cs[rl * 129 + 4 * c4 + 0];
      o.y = Cs[rl * 129 + 4 * c4 + 1];
      o.z = Cs[rl * 129 + 4 * c4 + 2];
      o.w = Cs[rl * 129 + 4 * c4 + 3];
      outv[(size_t)(rb + half * 64 + rl) * 2048 + (cb >> 2) + c4] = o;
    }
  }
}

// ---------------- K3: per-row top-31 via ballot-filtered insertion ---------
// One wave per row; cols scanned ascending (group then lane) -> identical
// stable lower-index-first tie semantics to the R8-verified serial merge.
// kmin refreshed via shfl from lane 0 (whose LDS reads are dependence-ordered
// after its own inserts) -- immune to compiler hoisting on other lanes.
__global__ __launch_bounds__(256) void topk_kernel(const float* __restrict__ sim,
                                                   float* __restrict__ vals,
                                                   int* __restrict__ inds) {
  __shared__ float kv[4][32];
  __shared__ int   ki[4][32];
  const int w = threadIdx.x >> 6;
  const int lane = threadIdx.x & 63;
  const int row = blockIdx.x * 4 + w;
  if (lane < KP1) { kv[w][lane] = -1e30f; ki[w][lane] = 0; }
  __syncthreads();

  const float* srow = sim + (size_t)row * NN;
  float kmin = -1e30f;
  for (int grp = 0; grp < NN / 64; ++grp) {
    float v = srow[grp * 64 + lane];
    unsigned long long mask = __ballot(v > kmin);
    while (mask) {
      int src = __builtin_ctzll(mask);
      mask &= mask - 1;
      float vv = __shfl(v, src, 64);
      int cc = grp * 64 + src;
      if (vv > kmin) {
        if (lane == 0) {
          int pos = KP1 - 1;
          while (pos > 0 && kv[w][pos - 1] < vv) {
            kv[w][pos] = kv[w][pos - 1];
            ki[w][pos] = ki[w][pos - 1];
            --pos;
          }
          kv[w][pos] = vv;
          ki[w][pos] = cc;
        }
        kmin = __shfl(kv[w][KP1 - 1], 0, 64);
      }
    }
  }
  if (lane < KP1) {
    vals[(size_t)row * KP1 + lane] = kv[w][lane];
    inds[row * KP1 + lane] = ki[w][lane];
  }
}

// ---------------- K4: degree mass (norm_row + norm_col) --------------------
__global__ __launch_bounds__(256) void norm_kernel(const float* __restrict__ vals,
                                                   const int* __restrict__ inds,
                                                   float* __restrict__ norm) {
  int i = blockIdx.x * blockDim.x + threadIdx.x;
  if (i >= NN) return;
  float s = 0.f;
  for (int t = 0; t < KP1; ++t) {
    float v = vals[i * KP1 + t];
    s += v;
    atomicAdd(&norm[inds[i * KP1 + t]], v);
  }
  atomicAdd(&norm[i], s);
}

// ---------------- K5: normalize + relu + threefry dropout + scatter --------
__global__ __launch_bounds__(256) void scatter_kernel(const float* __restrict__ vals,
                                                      const int* __restrict__ inds,
                                                      const float* __restrict__ norm,
                                                      float* __restrict__ out) {
  int e = blockIdx.x * blockDim.x + threadIdx.x;
  if (e >= HALF_EDGES) return;
  int i = e / KP1;
  int c = inds[e];
  float v = vals[e];
  float nv = v * (1.0f / sqrtf(norm[i])) * (1.0f / sqrtf(norm[c]));
  if (isnan(nv)) nv = 0.f;
  nv = fmaxf(nv, 0.f);
  float scaled = nv / 0.9f;
  if (keep_edge((uint32_t)e))
    atomicAdd(out + (size_t)i * NN + c, scaled);
  if (keep_edge((uint32_t)(e + HALF_EDGES)))
    atomicAdd(out + (size_t)c * NN + i, scaled);
}

// ---------------------------------------------------------------------------
extern "C" void kernel_launch(void* const* d_in, const int* in_sizes, int n_in,
                              void* d_out, int out_size, void* d_ws, size_t ws_size,
                              hipStream_t stream) {
  (void)in_sizes; (void)n_in; (void)ws_size;
  const float* x = (const float*)d_in[0];
  float* out = (float*)d_out;

  // ws layout (~2.1 MB, within proven budget)
  float* nrm  = (float*)d_ws;                  // 8192 floats
  float* vals = nrm + NN;                      // 253952 floats
  int*   inds = (int*)(vals + HALF_EDGES);     // 253952 ints
  float* norm = (float*)(inds + HALF_EDGES);   // 8192 floats

  hipLaunchKernelGGL(rownorm_kernel, dim3(NN / 16), dim3(256), 0, stream, x, nrm);
  // sims -> d_out (256 MB scratch, consumed by topk before the final memset)
  hipLaunchKernelGGL(gemm_kernel, dim3(64, 64), dim3(256), 65536, stream,
                     x, nrm, out);
  hipLaunchKernelGGL(topk_kernel, dim3(NN / 4), dim3(256), 0, stream,
                     out, vals, inds);
  hipMemsetAsync(norm, 0, NN * sizeof(float), stream);
  hipLaunchKernelGGL(norm_kernel, dim3((NN + 255) / 256), dim3(256), 0, stream,
                     vals, inds, norm);
  hipMemsetAsync(d_out, 0, (size_t)out_size * sizeof(float), stream);
  hipLaunchKernelGGL(scatter_kernel, dim3((HALF_EDGES + 255) / 256), dim3(256), 0, stream,
                     vals, inds, norm, out);
}

// Round 11
// 2216.851 us; speedup vs baseline: 2.1636x; 1.1926x over previous
//
#include <hip/hip_runtime.h>
#include <cstdint>
#include <cmath>

#define NN 8192
#define DD 512
#define KP1 31                      // k+1 with k=30
#define HALF_EDGES (NN * KP1)       // 253952

// ---------------- Threefry-2x32-20, key = (0, 42) --------------------------
__device__ __forceinline__ uint32_t rotl32(uint32_t v, int s) {
  return (v << s) | (v >> (32 - s));
}

__device__ __forceinline__ void threefry2x32_42(uint32_t x0, uint32_t x1,
                                                uint32_t& o0, uint32_t& o1) {
  const uint32_t ks0 = 0u, ks1 = 42u;
  const uint32_t ks2 = 0x1BD11BDAu ^ ks0 ^ ks1;
  x0 += ks0; x1 += ks1;
  x0 += x1; x1 = rotl32(x1, 13); x1 ^= x0;
  x0 += x1; x1 = rotl32(x1, 15); x1 ^= x0;
  x0 += x1; x1 = rotl32(x1, 26); x1 ^= x0;
  x0 += x1; x1 = rotl32(x1, 6);  x1 ^= x0;
  x0 += ks1; x1 += ks2 + 1u;
  x0 += x1; x1 = rotl32(x1, 17); x1 ^= x0;
  x0 += x1; x1 = rotl32(x1, 29); x1 ^= x0;
  x0 += x1; x1 = rotl32(x1, 16); x1 ^= x0;
  x0 += x1; x1 = rotl32(x1, 24); x1 ^= x0;
  x0 += ks2; x1 += ks0 + 2u;
  x0 += x1; x1 = rotl32(x1, 13); x1 ^= x0;
  x0 += x1; x1 = rotl32(x1, 15); x1 ^= x0;
  x0 += x1; x1 = rotl32(x1, 26); x1 ^= x0;
  x0 += x1; x1 = rotl32(x1, 6);  x1 ^= x0;
  x0 += ks0; x1 += ks1 + 3u;
  x0 += x1; x1 = rotl32(x1, 17); x1 ^= x0;
  x0 += x1; x1 = rotl32(x1, 29); x1 ^= x0;
  x0 += x1; x1 = rotl32(x1, 16); x1 ^= x0;
  x0 += x1; x1 = rotl32(x1, 24); x1 ^= x0;
  x0 += ks1; x1 += ks2 + 4u;
  x0 += x1; x1 = rotl32(x1, 13); x1 ^= x0;
  x0 += x1; x1 = rotl32(x1, 15); x1 ^= x0;
  x0 += x1; x1 = rotl32(x1, 26); x1 ^= x0;
  x0 += x1; x1 = rotl32(x1, 6);  x1 ^= x0;
  x0 += ks2; x1 += ks0 + 5u;
  o0 = x0; o1 = x1;
}

__device__ __forceinline__ bool keep_edge(uint32_t e) {
  uint32_t y0, y1;
  threefry2x32_42(0u, e, y0, y1);
  uint32_t bits = y0 ^ y1;
  float u = __uint_as_float((bits >> 9) | 0x3f800000u) - 1.0f;
  return u < 0.9f;
}

// ---------------- K1: fp32 row norm (numpy pairwise tree) ------------------
__global__ __launch_bounds__(256) void rownorm_kernel(const float* __restrict__ x,
                                                      float* __restrict__ nrm) {
#pragma clang fp contract(off)
  __shared__ float rowbuf[16][DD];
  __shared__ float partial[16][4];
  int tid = threadIdx.x;
  int rowbase = blockIdx.x * 16;

  for (int p = 0; p < 8; ++p) {
    int f = tid + p * 256;
    int r = f >> 7, k4 = f & 127;
    *(float4*)(&rowbuf[r][k4 << 2]) =
        *(const float4*)(x + (size_t)(rowbase + r) * DD + (k4 << 2));
  }
  __syncthreads();
  if (tid < 64) {
    int r = tid >> 2, q = tid & 3;
    const float* s = &rowbuf[r][q * 128];
    float a0 = s[0]*s[0], a1 = s[1]*s[1], a2 = s[2]*s[2], a3 = s[3]*s[3];
    float a4 = s[4]*s[4], a5 = s[5]*s[5], a6 = s[6]*s[6], a7 = s[7]*s[7];
    for (int i = 8; i < 128; i += 8) {
      a0 += s[i+0]*s[i+0]; a1 += s[i+1]*s[i+1];
      a2 += s[i+2]*s[i+2]; a3 += s[i+3]*s[i+3];
      a4 += s[i+4]*s[i+4]; a5 += s[i+5]*s[i+5];
      a6 += s[i+6]*s[i+6]; a7 += s[i+7]*s[i+7];
    }
    partial[r][q] = ((a0 + a1) + (a2 + a3)) + ((a4 + a5) + (a6 + a7));
  }
  __syncthreads();
  if (tid < 16) {
    float S = (partial[tid][0] + partial[tid][1]) + (partial[tid][2] + partial[tid][3]);
    nrm[rowbase + tid] = sqrtf(S);
  }
}

// ---------------- K2: upper-triangular 128x128 sim GEMM --------------------
// sim is bitwise symmetric (mul commutes, chain order identical), so only
// blocks with bx >= by are computed; off-diagonal results are written both
// straight and transposed. Per-element rounding: sequential mul+add chain,
// k ascending 0..511 (verified R8 contract, fp contract off).
__global__ __launch_bounds__(256, 2) void gemm_kernel(const float* __restrict__ x,
                                                      const float* __restrict__ nrm,
                                                      float* __restrict__ out) {
#pragma clang fp contract(off)
  if (blockIdx.x < blockIdx.y) return;       // lower triangle: skip
  extern __shared__ char smem[];
  float4* AsF4 = (float4*)smem;              // [128 rows][16 slots]  32 KB
  float4* BsF4 = (float4*)(smem + 32768);    // [128 cols][16 slots]  32 KB

  const int tid = threadIdx.x;
  const int rb = blockIdx.y * 128;
  const int cb = blockIdx.x * 128;
  const int m = tid & 15;                    // staging k4
  const int g = tid >> 4;                    // staging row/col base (0..15)

  float nA[8], nB[8];
  #pragma unroll
  for (int p = 0; p < 8; ++p) {
    nA[p] = nrm[rb + g + 16 * p];
    nB[p] = nrm[cb + g + 16 * p];
  }

  const int lane = tid & 63, wave = tid >> 6;
  const int wr = wave >> 1, wc = wave & 1;
  const int lr = lane >> 3, lc = lane & 7;
  const int r0 = wr * 64 + lr * 8;           // 8 contiguous rows r0..r0+7
  const int c0 = wc * 64 + lc;               // cols c0 + 8j, j=0..7
  const int rsw = r0 >> 3;                   // A-swizzle base (wr*8 + lr)

  float acc[8][8];
  #pragma unroll
  for (int i = 0; i < 8; ++i)
    #pragma unroll
    for (int j = 0; j < 8; ++j) acc[i][j] = 0.f;

  const float4* xv = (const float4*)x;

  for (int kc = 0; kc < 8; ++kc) {
    __syncthreads();
    #pragma unroll
    for (int p = 0; p < 8; ++p) {
      int r = g + 16 * p;                    // 0..127
      float4 va = xv[(size_t)(rb + r) * 128 + kc * 16 + m];
      va.x = va.x / nA[p]; va.y = va.y / nA[p];
      va.z = va.z / nA[p]; va.w = va.w / nA[p];
      AsF4[r * 16 + ((m + (r >> 3)) & 15)] = va;
      float4 vb = xv[(size_t)(cb + r) * 128 + kc * 16 + m];
      vb.x = vb.x / nB[p]; vb.y = vb.y / nB[p];
      vb.z = vb.z / nB[p]; vb.w = vb.w / nB[p];
      BsF4[r * 16 + ((m + r) & 15)] = vb;
    }
    __syncthreads();

    #pragma unroll 2
    for (int k4 = 0; k4 < 16; ++k4) {
      float4 av[8], bv[8];
      int tA = (k4 + rsw) & 15;
      #pragma unroll
      for (int i = 0; i < 8; ++i) av[i] = AsF4[(r0 + i) * 16 + tA];
      #pragma unroll
      for (int j = 0; j < 8; ++j)
        bv[j] = BsF4[(c0 + 8 * j) * 16 + ((k4 + lc + 8 * j) & 15)];
      #pragma unroll
      for (int kk = 0; kk < 4; ++kk) {
        #pragma unroll
        for (int i = 0; i < 8; ++i) {
          float a = ((const float*)&av[i])[kk];
          #pragma unroll
          for (int j = 0; j < 8; ++j) {
            float b = ((const float*)&bv[j])[kk];
            acc[i][j] = acc[i][j] + a * b;   // separate mul+add, k ascending
          }
        }
      }
    }
  }

  // Write-out via LDS re-tile (stride 129). Each half holds 64 rows x 128
  // cols of the tile; emit straight block, and transposed block if off-diag.
  float* Cs = (float*)smem;
  float4* outv = (float4*)out;
  const bool offdiag = (rb != cb);
  for (int half = 0; half < 2; ++half) {
    __syncthreads();
    if (wr == half) {
      #pragma unroll
      for (int i = 0; i < 8; ++i)
        #pragma unroll
        for (int j = 0; j < 8; ++j)
          Cs[(lr * 8 + i) * 129 + wc * 64 + 8 * j + lc] = acc[i][j];
    }
    __syncthreads();
    #pragma unroll
    for (int q = 0; q < 8; ++q) {            // straight: rows rb+64h+rl
      int f2 = tid + q * 256;
      int rl = f2 >> 5, c4 = f2 & 31;
      float4 o;
      o.x = Cs[rl * 129 + 4 * c4 + 0];
      o.y = Cs[rl * 129 + 4 * c4 + 1];
      o.z = Cs[rl * 129 + 4 * c4 + 2];
      o.w = Cs[rl * 129 + 4 * c4 + 3];
      outv[(size_t)(rb + half * 64 + rl) * 2048 + (cb >> 2) + c4] = o;
    }
    if (offdiag) {
      #pragma unroll
      for (int q = 0; q < 8; ++q) {          // transposed: rows cb+c,
        int f2 = tid + q * 256;              //   cols rb+64h .. +63
        int c = f2 >> 4, t4 = f2 & 15;
        float4 o;
        o.x = Cs[(4 * t4 + 0) * 129 + c];
        o.y = Cs[(4 * t4 + 1) * 129 + c];
        o.z = Cs[(4 * t4 + 2) * 129 + c];
        o.w = Cs[(4 * t4 + 3) * 129 + c];
        outv[(size_t)(cb + c) * 2048 + ((rb + half * 64) >> 2) + t4] = o;
      }
    }
  }
}

// ---------------- K3: per-row top-31 via ballot-filtered insertion ---------
__global__ __launch_bounds__(256) void topk_kernel(const float* __restrict__ sim,
                                                   float* __restrict__ vals,
                                                   int* __restrict__ inds) {
  __shared__ float kv[4][32];
  __shared__ int   ki[4][32];
  const int w = threadIdx.x >> 6;
  const int lane = threadIdx.x & 63;
  const int row = blockIdx.x * 4 + w;
  if (lane < KP1) { kv[w][lane] = -1e30f; ki[w][lane] = 0; }
  __syncthreads();

  const float* srow = sim + (size_t)row * NN;
  float kmin = -1e30f;
  for (int grp = 0; grp < NN / 64; ++grp) {
    float v = srow[grp * 64 + lane];
    unsigned long long mask = __ballot(v > kmin);
    while (mask) {
      int src = __builtin_ctzll(mask);
      mask &= mask - 1;
      float vv = __shfl(v, src, 64);
      int cc = grp * 64 + src;
      if (vv > kmin) {
        if (lane == 0) {
          int pos = KP1 - 1;
          while (pos > 0 && kv[w][pos - 1] < vv) {
            kv[w][pos] = kv[w][pos - 1];
            ki[w][pos] = ki[w][pos - 1];
            --pos;
          }
          kv[w][pos] = vv;
          ki[w][pos] = cc;
        }
        kmin = __shfl(kv[w][KP1 - 1], 0, 64);
      }
    }
  }
  if (lane < KP1) {
    vals[(size_t)row * KP1 + lane] = kv[w][lane];
    inds[row * KP1 + lane] = ki[w][lane];
  }
}

// ---------------- K4: degree mass (norm_row + norm_col) --------------------
__global__ __launch_bounds__(256) void norm_kernel(const float* __restrict__ vals,
                                                   const int* __restrict__ inds,
                                                   float* __restrict__ norm) {
  int i = blockIdx.x * blockDim.x + threadIdx.x;
  if (i >= NN) return;
  float s = 0.f;
  for (int t = 0; t < KP1; ++t) {
    float v = vals[i * KP1 + t];
    s += v;
    atomicAdd(&norm[inds[i * KP1 + t]], v);
  }
  atomicAdd(&norm[i], s);
}

// ---------------- K5: normalize + relu + threefry dropout + scatter --------
__global__ __launch_bounds__(256) void scatter_kernel(const float* __restrict__ vals,
                                                      const int* __restrict__ inds,
                                                      const float* __restrict__ norm,
                                                      float* __restrict__ out) {
  int e = blockIdx.x * blockDim.x + threadIdx.x;
  if (e >= HALF_EDGES) return;
  int i = e / KP1;
  int c = inds[e];
  float v = vals[e];
  float nv = v * (1.0f / sqrtf(norm[i])) * (1.0f / sqrtf(norm[c]));
  if (isnan(nv)) nv = 0.f;
  nv = fmaxf(nv, 0.f);
  float scaled = nv / 0.9f;
  if (keep_edge((uint32_t)e))
    atomicAdd(out + (size_t)i * NN + c, scaled);
  if (keep_edge((uint32_t)(e + HALF_EDGES)))
    atomicAdd(out + (size_t)c * NN + i, scaled);
}

// ---------------------------------------------------------------------------
extern "C" void kernel_launch(void* const* d_in, const int* in_sizes, int n_in,
                              void* d_out, int out_size, void* d_ws, size_t ws_size,
                              hipStream_t stream) {
  (void)in_sizes; (void)n_in; (void)ws_size;
  const float* x = (const float*)d_in[0];
  float* out = (float*)d_out;

  // ws layout (~2.1 MB, within proven budget)
  float* nrm  = (float*)d_ws;                  // 8192 floats
  float* vals = nrm + NN;                      // 253952 floats
  int*   inds = (int*)(vals + HALF_EDGES);     // 253952 ints
  float* norm = (float*)(inds + HALF_EDGES);   // 8192 floats

  hipLaunchKernelGGL(rownorm_kernel, dim3(NN / 16), dim3(256), 0, stream, x, nrm);
  // sims -> d_out (256 MB scratch, consumed by topk before the final memset)
  hipLaunchKernelGGL(gemm_kernel, dim3(64, 64), dim3(256), 65536, stream,
                     x, nrm, out);
  hipLaunchKernelGGL(topk_kernel, dim3(NN / 4), dim3(256), 0, stream,
                     out, vals, inds);
  hipMemsetAsync(norm, 0, NN * sizeof(float), stream);
  hipLaunchKernelGGL(norm_kernel, dim3((NN + 255) / 256), dim3(256), 0, stream,
                     vals, inds, norm);
  hipMemsetAsync(d_out, 0, (size_t)out_size * sizeof(float), stream);
  hipLaunchKernelGGL(scatter_kernel, dim3((HALF_EDGES + 255) / 256), dim3(256), 0, stream,
                     vals, inds, norm, out);
}

// Round 12
// 1300.429 us; speedup vs baseline: 3.6883x; 1.7047x over previous
//
#include <hip/hip_runtime.h>
#include <cstdint>
#include <cmath>

#define NN 8192
#define DD 512
#define KP1 31                      // k+1 with k=30
#define HALF_EDGES (NN * KP1)       // 253952

// ---------------- Threefry-2x32-20, key = (0, 42) --------------------------
__device__ __forceinline__ uint32_t rotl32(uint32_t v, int s) {
  return (v << s) | (v >> (32 - s));
}

__device__ __forceinline__ void threefry2x32_42(uint32_t x0, uint32_t x1,
                                                uint32_t& o0, uint32_t& o1) {
  const uint32_t ks0 = 0u, ks1 = 42u;
  const uint32_t ks2 = 0x1BD11BDAu ^ ks0 ^ ks1;
  x0 += ks0; x1 += ks1;
  x0 += x1; x1 = rotl32(x1, 13); x1 ^= x0;
  x0 += x1; x1 = rotl32(x1, 15); x1 ^= x0;
  x0 += x1; x1 = rotl32(x1, 26); x1 ^= x0;
  x0 += x1; x1 = rotl32(x1, 6);  x1 ^= x0;
  x0 += ks1; x1 += ks2 + 1u;
  x0 += x1; x1 = rotl32(x1, 17); x1 ^= x0;
  x0 += x1; x1 = rotl32(x1, 29); x1 ^= x0;
  x0 += x1; x1 = rotl32(x1, 16); x1 ^= x0;
  x0 += x1; x1 = rotl32(x1, 24); x1 ^= x0;
  x0 += ks2; x1 += ks0 + 2u;
  x0 += x1; x1 = rotl32(x1, 13); x1 ^= x0;
  x0 += x1; x1 = rotl32(x1, 15); x1 ^= x0;
  x0 += x1; x1 = rotl32(x1, 26); x1 ^= x0;
  x0 += x1; x1 = rotl32(x1, 6);  x1 ^= x0;
  x0 += ks0; x1 += ks1 + 3u;
  x0 += x1; x1 = rotl32(x1, 17); x1 ^= x0;
  x0 += x1; x1 = rotl32(x1, 29); x1 ^= x0;
  x0 += x1; x1 = rotl32(x1, 16); x1 ^= x0;
  x0 += x1; x1 = rotl32(x1, 24); x1 ^= x0;
  x0 += ks1; x1 += ks2 + 4u;
  x0 += x1; x1 = rotl32(x1, 13); x1 ^= x0;
  x0 += x1; x1 = rotl32(x1, 15); x1 ^= x0;
  x0 += x1; x1 = rotl32(x1, 26); x1 ^= x0;
  x0 += x1; x1 = rotl32(x1, 6);  x1 ^= x0;
  x0 += ks2; x1 += ks0 + 5u;
  o0 = x0; o1 = x1;
}

__device__ __forceinline__ bool keep_edge(uint32_t e) {
  uint32_t y0, y1;
  threefry2x32_42(0u, e, y0, y1);
  uint32_t bits = y0 ^ y1;
  float u = __uint_as_float((bits >> 9) | 0x3f800000u) - 1.0f;
  return u < 0.9f;
}

// ---------------- K1: fp32 row norm (numpy pairwise tree) ------------------
__global__ __launch_bounds__(256) void rownorm_kernel(const float* __restrict__ x,
                                                      float* __restrict__ nrm) {
#pragma clang fp contract(off)
  __shared__ float rowbuf[16][DD];
  __shared__ float partial[16][4];
  int tid = threadIdx.x;
  int rowbase = blockIdx.x * 16;

  for (int p = 0; p < 8; ++p) {
    int f = tid + p * 256;
    int r = f >> 7, k4 = f & 127;
    *(float4*)(&rowbuf[r][k4 << 2]) =
        *(const float4*)(x + (size_t)(rowbase + r) * DD + (k4 << 2));
  }
  __syncthreads();
  if (tid < 64) {
    int r = tid >> 2, q = tid & 3;
    const float* s = &rowbuf[r][q * 128];
    float a0 = s[0]*s[0], a1 = s[1]*s[1], a2 = s[2]*s[2], a3 = s[3]*s[3];
    float a4 = s[4]*s[4], a5 = s[5]*s[5], a6 = s[6]*s[6], a7 = s[7]*s[7];
    for (int i = 8; i < 128; i += 8) {
      a0 += s[i+0]*s[i+0]; a1 += s[i+1]*s[i+1];
      a2 += s[i+2]*s[i+2]; a3 += s[i+3]*s[i+3];
      a4 += s[i+4]*s[i+4]; a5 += s[i+5]*s[i+5];
      a6 += s[i+6]*s[i+6]; a7 += s[i+7]*s[i+7];
    }
    partial[r][q] = ((a0 + a1) + (a2 + a3)) + ((a4 + a5) + (a6 + a7));
  }
  __syncthreads();
  if (tid < 16) {
    float S = (partial[tid][0] + partial[tid][1]) + (partial[tid][2] + partial[tid][3]);
    nrm[rowbase + tid] = sqrtf(S);
  }
}

// ---------------- K2: upper-triangular 128x128 sim GEMM, reg-prefetch ------
// Compact launch: 2080 blocks, bid -> (by, bx) with bx >= by. sim is bitwise
// symmetric -> off-diag tiles written straight + transposed. Per-element
// rounding: sequential mul+add chain, k ascending (verified R8 contract).
__global__ __launch_bounds__(256, 2) void gemm_kernel(const float* __restrict__ x,
                                                      const float* __restrict__ nrm,
                                                      float* __restrict__ out) {
#pragma clang fp contract(off)
  // ---- triangular block index
  int bid = blockIdx.x;
  int by = (int)((129.0f - sqrtf(16641.0f - 8.0f * (float)bid)) * 0.5f);
  while (64 * by - (by * (by - 1)) / 2 > bid) --by;
  while (64 * (by + 1) - ((by + 1) * by) / 2 <= bid) ++by;
  const int bx = by + (bid - (64 * by - (by * (by - 1)) / 2));

  extern __shared__ char smem[];
  float4* AsF4 = (float4*)smem;              // [128 rows][16 slots]  32 KB
  float4* BsF4 = (float4*)(smem + 32768);    // [128 cols][16 slots]  32 KB

  const int tid = threadIdx.x;
  const int rb = by * 128;
  const int cb = bx * 128;
  const int m = tid & 15;                    // staging k4
  const int g = tid >> 4;                    // staging row/col base (0..15)

  float nA[8], nB[8];
  #pragma unroll
  for (int p = 0; p < 8; ++p) {
    nA[p] = nrm[rb + g + 16 * p];
    nB[p] = nrm[cb + g + 16 * p];
  }

  const int lane = tid & 63, wave = tid >> 6;
  const int wr = wave >> 1, wc = wave & 1;
  const int lr = lane >> 3, lc = lane & 7;
  const int r0 = wr * 64 + lr * 8;
  const int c0 = wc * 64 + lc;
  const int rsw = r0 >> 3;

  float acc[8][8];
  #pragma unroll
  for (int i = 0; i < 8; ++i)
    #pragma unroll
    for (int j = 0; j < 8; ++j) acc[i][j] = 0.f;

  const float4* xv = (const float4*)x;

  // prologue: prefetch kc=0 raw tiles into registers
  float4 ra[8], rbv[8];
  #pragma unroll
  for (int p = 0; p < 8; ++p) {
    int r = g + 16 * p;
    ra[p]  = xv[(size_t)(rb + r) * 128 + m];
    rbv[p] = xv[(size_t)(cb + r) * 128 + m];
  }

  for (int kc = 0; kc < 8; ++kc) {
    __syncthreads();                         // LDS consumers of prev tile done
    #pragma unroll
    for (int p = 0; p < 8; ++p) {            // div (exact) + store to LDS
      int r = g + 16 * p;
      float4 va = ra[p];
      va.x = va.x / nA[p]; va.y = va.y / nA[p];
      va.z = va.z / nA[p]; va.w = va.w / nA[p];
      AsF4[r * 16 + ((m + (r >> 3)) & 15)] = va;
      float4 vb = rbv[p];
      vb.x = vb.x / nB[p]; vb.y = vb.y / nB[p];
      vb.z = vb.z / nB[p]; vb.w = vb.w / nB[p];
      BsF4[r * 16 + ((m + r) & 15)] = vb;
    }
    __syncthreads();
    if (kc < 7) {                            // prefetch next tile (overlaps compute)
      #pragma unroll
      for (int p = 0; p < 8; ++p) {
        int r = g + 16 * p;
        ra[p]  = xv[(size_t)(rb + r) * 128 + (kc + 1) * 16 + m];
        rbv[p] = xv[(size_t)(cb + r) * 128 + (kc + 1) * 16 + m];
      }
    }

    #pragma unroll 2
    for (int k4 = 0; k4 < 16; ++k4) {
      float4 av[8], bv[8];
      int tA = (k4 + rsw) & 15;
      #pragma unroll
      for (int i = 0; i < 8; ++i) av[i] = AsF4[(r0 + i) * 16 + tA];
      #pragma unroll
      for (int j = 0; j < 8; ++j)
        bv[j] = BsF4[(c0 + 8 * j) * 16 + ((k4 + lc + 8 * j) & 15)];
      #pragma unroll
      for (int kk = 0; kk < 4; ++kk) {
        #pragma unroll
        for (int i = 0; i < 8; ++i) {
          float a = ((const float*)&av[i])[kk];
          #pragma unroll
          for (int j = 0; j < 8; ++j) {
            float b = ((const float*)&bv[j])[kk];
            acc[i][j] = acc[i][j] + a * b;   // separate mul+add, k ascending
          }
        }
      }
    }
  }

  // Write-out via LDS re-tile (stride 129): straight + transposed (off-diag).
  float* Cs = (float*)smem;
  float4* outv = (float4*)out;
  const bool offdiag = (rb != cb);
  for (int half = 0; half < 2; ++half) {
    __syncthreads();
    if (wr == half) {
      #pragma unroll
      for (int i = 0; i < 8; ++i)
        #pragma unroll
        for (int j = 0; j < 8; ++j)
          Cs[(lr * 8 + i) * 129 + wc * 64 + 8 * j + lc] = acc[i][j];
    }
    __syncthreads();
    #pragma unroll
    for (int q = 0; q < 8; ++q) {
      int f2 = tid + q * 256;
      int rl = f2 >> 5, c4 = f2 & 31;
      float4 o;
      o.x = Cs[rl * 129 + 4 * c4 + 0];
      o.y = Cs[rl * 129 + 4 * c4 + 1];
      o.z = Cs[rl * 129 + 4 * c4 + 2];
      o.w = Cs[rl * 129 + 4 * c4 + 3];
      outv[(size_t)(rb + half * 64 + rl) * 2048 + (cb >> 2) + c4] = o;
    }
    if (offdiag) {
      #pragma unroll
      for (int q = 0; q < 8; ++q) {
        int f2 = tid + q * 256;
        int c = f2 >> 4, t4 = f2 & 15;
        float4 o;
        o.x = Cs[(4 * t4 + 0) * 129 + c];
        o.y = Cs[(4 * t4 + 1) * 129 + c];
        o.z = Cs[(4 * t4 + 2) * 129 + c];
        o.w = Cs[(4 * t4 + 3) * 129 + c];
        outv[(size_t)(cb + c) * 2048 + ((rb + half * 64) >> 2) + t4] = o;
      }
    }
  }
}

// ---------------- K3: per-row top-31, lane-registered O(1) insertion -------
// One wave per row. Slot s lives in lane s (s<31): kval/kidx registers,
// sorted desc. Candidates processed in ascending col order (group asc, ctz
// asc) -> identical stable lower-index-first tie semantics to the R8-verified
// merge: entry is strict (vv > kmin), position = #slots with kval >= vv.
__global__ __launch_bounds__(256) void topk_kernel(const float* __restrict__ sim,
                                                   float* __restrict__ vals,
                                                   int* __restrict__ inds) {
  const int w = threadIdx.x >> 6;
  const int lane = threadIdx.x & 63;
  const int row = blockIdx.x * 4 + w;

  float kval = -1e30f;
  int   kidx = 0;
  float kmin = -1e30f;

  const float* srow = sim + (size_t)row * NN;
  for (int grp = 0; grp < NN / 64; ++grp) {
    float v = srow[grp * 64 + lane];
    unsigned long long mask = __ballot(v > kmin);
    while (mask) {
      int src = __builtin_ctzll(mask);
      mask &= mask - 1;
      float vv = __shfl(v, src, 64);          // wave-uniform candidate
      if (vv > kmin) {
        int cc = grp * 64 + src;
        unsigned long long ge = __ballot(kval >= vv) & 0x7FFFFFFFull;
        int pos = __popcll(ge);               // slots strictly before vv
        float upv = __shfl_up(kval, 1, 64);
        int   upi = __shfl_up(kidx, 1, 64);
        if (lane < KP1) {
          if (lane == pos) { kval = vv; kidx = cc; }
          else if (lane > pos) { kval = upv; kidx = upi; }
        }
        kmin = __shfl(kval, KP1 - 1, 64);
      }
    }
  }
  if (lane < KP1) {
    vals[(size_t)row * KP1 + lane] = kval;
    inds[row * KP1 + lane] = kidx;
  }
}

// ---------------- K4: degree mass (norm_row + norm_col) --------------------
__global__ __launch_bounds__(256) void norm_kernel(const float* __restrict__ vals,
                                                   const int* __restrict__ inds,
                                                   float* __restrict__ norm) {
  int i = blockIdx.x * blockDim.x + threadIdx.x;
  if (i >= NN) return;
  float s = 0.f;
  for (int t = 0; t < KP1; ++t) {
    float v = vals[i * KP1 + t];
    s += v;
    atomicAdd(&norm[inds[i * KP1 + t]], v);
  }
  atomicAdd(&norm[i], s);
}

// ---------------- K5: normalize + relu + threefry dropout + scatter --------
__global__ __launch_bounds__(256) void scatter_kernel(const float* __restrict__ vals,
                                                      const int* __restrict__ inds,
                                                      const float* __restrict__ norm,
                                                      float* __restrict__ out) {
  int e = blockIdx.x * blockDim.x + threadIdx.x;
  if (e >= HALF_EDGES) return;
  int i = e / KP1;
  int c = inds[e];
  float v = vals[e];
  float nv = v * (1.0f / sqrtf(norm[i])) * (1.0f / sqrtf(norm[c]));
  if (isnan(nv)) nv = 0.f;
  nv = fmaxf(nv, 0.f);
  float scaled = nv / 0.9f;
  if (keep_edge((uint32_t)e))
    atomicAdd(out + (size_t)i * NN + c, scaled);
  if (keep_edge((uint32_t)(e + HALF_EDGES)))
    atomicAdd(out + (size_t)c * NN + i, scaled);
}

// ---------------------------------------------------------------------------
extern "C" void kernel_launch(void* const* d_in, const int* in_sizes, int n_in,
                              void* d_out, int out_size, void* d_ws, size_t ws_size,
                              hipStream_t stream) {
  (void)in_sizes; (void)n_in; (void)ws_size;
  const float* x = (const float*)d_in[0];
  float* out = (float*)d_out;

  // ws layout (~2.1 MB, within proven budget)
  float* nrm  = (float*)d_ws;                  // 8192 floats
  float* vals = nrm + NN;                      // 253952 floats
  int*   inds = (int*)(vals + HALF_EDGES);     // 253952 ints
  float* norm = (float*)(inds + HALF_EDGES);   // 8192 floats

  hipLaunchKernelGGL(rownorm_kernel, dim3(NN / 16), dim3(256), 0, stream, x, nrm);
  // sims -> d_out (256 MB scratch, consumed by topk before the final memset)
  hipLaunchKernelGGL(gemm_kernel, dim3(2080), dim3(256), 65536, stream,
                     x, nrm, out);
  hipLaunchKernelGGL(topk_kernel, dim3(NN / 4), dim3(256), 0, stream,
                     out, vals, inds);
  hipMemsetAsync(norm, 0, NN * sizeof(float), stream);
  hipLaunchKernelGGL(norm_kernel, dim3((NN + 255) / 256), dim3(256), 0, stream,
                     vals, inds, norm);
  hipMemsetAsync(d_out, 0, (size_t)out_size * sizeof(float), stream);
  hipLaunchKernelGGL(scatter_kernel, dim3((HALF_EDGES + 255) / 256), dim3(256), 0, stream,
                     vals, inds, norm, out);
}